// Round 2
// baseline (160.491 us; speedup 1.0000x reference)
//
#include <hip/hip_runtime.h>

// Problem constants (from reference): B=32, M=32, C=1024, R=28
#define Rr 28
#define Bb 32
#define Mm 32
#define Cc 1024

#define NROWS (Bb * Cc * Rr)       // 917504 rows of F (each 28 contiguous floats)
#define NCOLS (Bb * Mm * Rr)       // 28672 columns of Masks (stride 28)
#define ROWS_PER_BLK 256
#define ROWBLKS (NROWS / ROWS_PER_BLK)  // 3584
#define COLBLKS (NCOLS / 256)           // 112

// Fused reduction kernel.
// Row part: block stages 256 rows (7168 floats = 1792 float4) into LDS with
// fully coalesced float4 loads (lane-consecutive float4 indices), scattered
// into a stride-29-padded tile. Then thread t sums row t from LDS (stride-29
// read: lanes t and t+32 share a bank -> 2-way, free) and stores coalesced.
// This replaces the round-1 pattern where each lane's float4 hit a different
// cache line (112 B lane stride -> 64 lines/instruction, request-rate bound).
__global__ __launch_bounds__(256) void reduce_both(
    const float* __restrict__ F, const float* __restrict__ Mk,
    float* __restrict__ rowbuf, float* __restrict__ colbuf) {
    int bid = blockIdx.x;
    if (bid < ROWBLKS) {
        __shared__ float tile[ROWS_PER_BLK * 29];   // 29696 B
        const int t = threadIdx.x;
        const float4* g = (const float4*)(F + (size_t)bid * (ROWS_PER_BLK * Rr));
#pragma unroll
        for (int q = 0; q < 7; ++q) {
            int f = t + 256 * q;          // float4 index in tile, lane-consecutive
            float4 v = g[f];
            int r = f / 7;                // row (28 floats = 7 float4 per row)
            int j = 4 * (f - r * 7);      // float offset within row
            float* d = &tile[r * 29 + j];
            d[0] = v.x; d[1] = v.y; d[2] = v.z; d[3] = v.w;
        }
        __syncthreads();
        float s = 0.f;
#pragma unroll
        for (int j = 0; j < Rr; ++j) s += tile[t * 29 + j];
        rowbuf[(size_t)bid * ROWS_PER_BLK + t] = s;
    } else {
        // Masks column sums: col[b,m,r] = sum_i Mk[b,m,i,r]
        // lane-consecutive t -> consecutive r -> coalesced (28-float runs).
        int t = (bid - ROWBLKS) * 256 + threadIdx.x;
        int bm = t / Rr;
        int r  = t - bm * Rr;
        const float* p = Mk + (size_t)bm * (Rr * Rr) + r;
        float s = 0.f;
#pragma unroll
        for (int i = 0; i < Rr; ++i) s += p[i * Rr];
        colbuf[t] = s;
    }
}

// Batched tiny GEMM: S[b,m,c] = (1/784) * sum_r col[b,m,r] * row[b,c,r]
// grid = 32 batches x 8 c-tiles of 128. LDS staging, stride padded 28->29.
#define CT 128
__global__ __launch_bounds__(256) void small_gemm(
    const float* __restrict__ colbuf, const float* __restrict__ rowbuf,
    float* __restrict__ S) {
    __shared__ float col_s[Mm * 29];
    __shared__ float row_s[CT * 29];
    const int b  = blockIdx.x >> 3;
    const int c0 = (blockIdx.x & 7) * CT;
    const int t  = threadIdx.x;

    for (int idx = t; idx < Mm * Rr; idx += 256) {
        int m = idx / Rr, r = idx - m * Rr;
        col_s[m * 29 + r] = colbuf[(size_t)b * Mm * Rr + idx];
    }
    for (int idx = t; idx < CT * Rr; idx += 256) {
        int cl = idx / Rr, r = idx - cl * Rr;
        row_s[cl * 29 + r] = rowbuf[((size_t)b * Cc + c0) * Rr + idx];
    }
    __syncthreads();

    const int cl = t & (CT - 1);   // c within tile (lane-consecutive -> coalesced stores)
    const int mh = t >> 7;         // 0 or 1, wave-uniform
    float rreg[Rr];
#pragma unroll
    for (int r = 0; r < Rr; ++r) rreg[r] = row_s[cl * 29 + r];

    const float inv = 1.0f / (Rr * Rr);
    for (int m = mh; m < Mm; m += 2) {
        float acc = 0.f;
#pragma unroll
        for (int r = 0; r < Rr; ++r)
            acc += col_s[m * 29 + r] * rreg[r];   // wave-uniform broadcast (free)
        S[((size_t)b * Mm + m) * Cc + c0 + cl] = acc * inv;
    }
}

extern "C" void kernel_launch(void* const* d_in, const int* in_sizes, int n_in,
                              void* d_out, int out_size, void* d_ws, size_t ws_size,
                              hipStream_t stream) {
    const float* F  = (const float*)d_in[0];   // (B, C, R, R) fp32
    const float* Mk = (const float*)d_in[1];   // (B, M, R, R) fp32
    float* S = (float*)d_out;                  // (B, M, C) fp32

    float* rowbuf = (float*)d_ws;              // B*C*R floats = 3.67 MB
    float* colbuf = rowbuf + NROWS;            // B*M*R floats = 114 KB

    reduce_both<<<ROWBLKS + COLBLKS, 256, 0, stream>>>(F, Mk, rowbuf, colbuf);
    small_gemm<<<Bb * 8, 256, 0, stream>>>(colbuf, rowbuf, S);
}